// Round 5
// baseline (177.580 us; speedup 1.0000x reference)
//
#include <hip/hip_runtime.h>

// CIN forward: B=2048, F=32, DIM=64, layers (128,128)
// out[b, 0:64]   = sum_d relu(W0 @ z0 + b0)[64:128, d]
// out[b, 64:192] = sum_d relu(W1 @ z1 + b1)[0:128, d]
// z0[h*32+m, d] = x[h,d]*x[m,d];  z1[h*32+m, d] = h1[h,d]*x[m,d]
//
// R5: 32x32x16_f16, 32 rows x 64 cols per wave (acc=32 AGPRs), 4 waves/batch,
// grid 2048 (1 batch/block, 2 clean phases at 4 blocks/CU), explicit
// distance-2 register prefetch of A-fragments + scalars to cover L2 latency.

#define K0 1024
#define K1 2048
#define OUTC 192
#define L0_ELEMS (128 * K0)      // 131072
#define L1_ELEMS (128 * K1)      // 262144
#define L0_FRAGS (L0_ELEMS / 8)  // 16384
#define L1_FRAGS (L1_ELEMS / 8)  // 32768

typedef _Float16 v8h  __attribute__((ext_vector_type(8)));
typedef _Float16 v2h  __attribute__((ext_vector_type(2)));
typedef float    v16f __attribute__((ext_vector_type(16)));

// Swizzled W (f16): frag t = ks*256 + rt*64 + lane holds
//   W[row = rt*32 + (lane&31)][k = ks*16 + (lane>>5)*8 + j],  j=0..7
__global__ void convert_w_kernel(const float* __restrict__ W0,
                                 const float* __restrict__ W1,
                                 _Float16* __restrict__ wsw) {
    int t = blockIdx.x * blockDim.x + threadIdx.x;
    if (t >= L0_FRAGS + L1_FRAGS) return;
    const float* src;
    _Float16* dst;
    if (t < L0_FRAGS) {
        int lane = t & 63, rt = (t >> 6) & 3, ks = t >> 8;
        int row = rt * 32 + (lane & 31);
        int k   = ks * 16 + (lane >> 5) * 8;
        src = W0 + (size_t)row * K0 + k;
        dst = wsw + (size_t)t * 8;
    } else {
        int u = t - L0_FRAGS;
        int lane = u & 63, rt = (u >> 6) & 3, ks = u >> 8;
        int row = rt * 32 + (lane & 31);
        int k   = ks * 16 + (lane >> 5) * 8;
        src = W1 + (size_t)row * K1 + k;
        dst = wsw + L0_ELEMS + (size_t)u * 8;
    }
    #pragma unroll
    for (int j = 0; j < 8; ++j) dst[j] = (_Float16)src[j];
}

// duplicate a u16 f16 scalar into all 8 elems of a v8h (1 VALU: lshl_or)
__device__ __forceinline__ v8h dupscalar(uint32_t u) {
    uint32_t pair = (u << 16) | u;
    v2h p = __builtin_bit_cast(v2h, pair);
    return __builtin_shufflevector(p, p, 0, 1, 0, 1, 0, 1, 0, 1);
}

#define MFMA32(A, B, C) __builtin_amdgcn_mfma_f32_32x32x16_f16((A), (B), (C), 0, 0, 0)

__global__ __launch_bounds__(256, 4) void cin_kernel(
    const float* __restrict__ X,      // (B, 32, 64) fp32
    const float* __restrict__ b0,     // (128,)
    const float* __restrict__ b1,     // (128,)
    const _Float16* __restrict__ Wsw, // swizzled W0 | W1 (f16)
    float* __restrict__ out)          // (B, 192) fp32
{
    __shared__ uint16_t xS[32 * 64];   // x[m][d] f16 bits, 4 KB
    __shared__ uint16_t h1S[64 * 64];  // h1[h][d] f16 bits, 8 KB; xT(pitch40) overlay at init
    __shared__ float biasLds[256];     // b0 | b1

    const int tid  = threadIdx.x;
    const int wave = tid >> 6;   // row-quarter: rows wave*32 .. +31
    const int lane = tid & 63;
    const int l31  = lane & 31;
    const int hi   = lane >> 5;  // k-octet selector
    const size_t b = blockIdx.x;

    if (tid < 128) biasLds[tid] = b0[tid];
    else           biasLds[tid] = b1[tid - 128];

    // ---- stage x: xT (f16 pitch-40, overlaid in h1S) + xS (u16) ----
    const float* xsrc = X + b * 2048;
    for (int i = tid; i < 2048; i += 256) {
        int m = i >> 6, d = i & 63;
        _Float16 h = (_Float16)xsrc[i];
        ((_Float16*)h1S)[d * 40 + m] = h;
        xS[m * 64 + d] = __builtin_bit_cast(uint16_t, h);
    }
    __syncthreads();

    // K-invariant B vector parts: xv[c][p] = x[m = p*16 + hi*8 .. +7][d = c*32 + l31]
    v8h xv[2][2];
    {
        const _Float16* xT = (const _Float16*)h1S;
        #pragma unroll
        for (int c = 0; c < 2; ++c)
            #pragma unroll
            for (int p = 0; p < 2; ++p)
                xv[c][p] = *(const v8h*)&xT[(c * 32 + l31) * 40 + p * 16 + hi * 8];
    }
    __syncthreads();  // xv reads complete before h1S overlay is rewritten

    // ================= layer 0 (H=32) =================
    v16f acc0 = (v16f)0.0f, acc1 = (v16f)0.0f;  // c=0, c=1
    {
        const _Float16* Wb = Wsw + (size_t)wave * 512 + (size_t)lane * 8;
        // prologue: h=0,1 in flight
        v8h Ap0 = *(const v8h*)(Wb);
        v8h Ap1 = *(const v8h*)(Wb + 2048);
        v8h Bp0 = *(const v8h*)(Wb + 4096);
        v8h Bp1 = *(const v8h*)(Wb + 4096 + 2048);
        uint32_t ua0 = xS[l31],      ua1 = xS[32 + l31];
        uint32_t ub0 = xS[64 + l31], ub1 = xS[64 + 32 + l31];
        #pragma unroll 2
        for (int h = 0; h < 32; ++h) {
            int hn = (h + 2 < 32) ? h + 2 : 31;
            v8h P0 = *(const v8h*)(Wb + (size_t)hn * 4096);
            v8h P1 = *(const v8h*)(Wb + (size_t)hn * 4096 + 2048);
            uint32_t w0 = xS[hn * 64 + l31];
            uint32_t w1 = xS[hn * 64 + 32 + l31];
            v8h s80 = dupscalar(ua0), s81 = dupscalar(ua1);
            v8h b00 = s80 * xv[0][0];
            v8h b10 = s81 * xv[1][0];
            acc0 = MFMA32(Ap0, b00, acc0);
            acc1 = MFMA32(Ap0, b10, acc1);
            v8h b01 = s80 * xv[0][1];
            v8h b11 = s81 * xv[1][1];
            acc0 = MFMA32(Ap1, b01, acc0);
            acc1 = MFMA32(Ap1, b11, acc1);
            Ap0 = Bp0; Ap1 = Bp1; Bp0 = P0; Bp1 = P1;
            ua0 = ub0; ua1 = ub1; ub0 = w0; ub1 = w1;
        }
    }

    // ---- epilogue 0 ----
    if (wave < 2) {
        // rows 0..63 -> h1S (u16)
        #pragma unroll
        for (int reg = 0; reg < 16; ++reg) {
            int row = wave * 32 + (reg & 3) + 8 * (reg >> 2) + 4 * hi;
            float bias = biasLds[row];
            float v0 = acc0[reg] + bias;
            float v1 = acc1[reg] + bias;
            v0 = v0 > 0.0f ? v0 : 0.0f;
            v1 = v1 > 0.0f ? v1 : 0.0f;
            h1S[row * 64 + l31]      = __builtin_bit_cast(uint16_t, (_Float16)v0);
            h1S[row * 64 + 32 + l31] = __builtin_bit_cast(uint16_t, (_Float16)v1);
        }
    } else {
        // rows 64..127 -> out[b][row-64]
        #pragma unroll
        for (int reg = 0; reg < 16; ++reg) {
            int grow = wave * 32 + (reg & 3) + 8 * (reg >> 2) + 4 * hi;
            float bias = biasLds[grow];
            float v0 = acc0[reg] + bias;
            float v1 = acc1[reg] + bias;
            float s = (v0 > 0.0f ? v0 : 0.0f) + (v1 > 0.0f ? v1 : 0.0f);
            s += __shfl_xor(s, 1);
            s += __shfl_xor(s, 2);
            s += __shfl_xor(s, 4);
            s += __shfl_xor(s, 8);
            s += __shfl_xor(s, 16);
            if (l31 == 0) out[b * OUTC + (grow - 64)] = s;
        }
    }
    __syncthreads();

    // ================= layer 1 (H=64) =================
    acc0 = (v16f)0.0f; acc1 = (v16f)0.0f;
    {
        const _Float16* Wb = Wsw + L0_ELEMS + (size_t)wave * 512 + (size_t)lane * 8;
        v8h Ap0 = *(const v8h*)(Wb);
        v8h Ap1 = *(const v8h*)(Wb + 2048);
        v8h Bp0 = *(const v8h*)(Wb + 4096);
        v8h Bp1 = *(const v8h*)(Wb + 4096 + 2048);
        uint32_t ua0 = h1S[l31],      ua1 = h1S[32 + l31];
        uint32_t ub0 = h1S[64 + l31], ub1 = h1S[64 + 32 + l31];
        #pragma unroll 2
        for (int h = 0; h < 64; ++h) {
            int hn = (h + 2 < 64) ? h + 2 : 63;
            v8h P0 = *(const v8h*)(Wb + (size_t)hn * 4096);
            v8h P1 = *(const v8h*)(Wb + (size_t)hn * 4096 + 2048);
            uint32_t w0 = h1S[hn * 64 + l31];
            uint32_t w1 = h1S[hn * 64 + 32 + l31];
            v8h s80 = dupscalar(ua0), s81 = dupscalar(ua1);
            v8h b00 = s80 * xv[0][0];
            v8h b10 = s81 * xv[1][0];
            acc0 = MFMA32(Ap0, b00, acc0);
            acc1 = MFMA32(Ap0, b10, acc1);
            v8h b01 = s80 * xv[0][1];
            v8h b11 = s81 * xv[1][1];
            acc0 = MFMA32(Ap1, b01, acc0);
            acc1 = MFMA32(Ap1, b11, acc1);
            Ap0 = Bp0; Ap1 = Bp1; Bp0 = P0; Bp1 = P1;
            ua0 = ub0; ua1 = ub1; ub0 = w0; ub1 = w1;
        }
    }

    // ---- epilogue 1: all 128 rows -> out[b][64 + row] ----
    #pragma unroll
    for (int reg = 0; reg < 16; ++reg) {
        int grow = wave * 32 + (reg & 3) + 8 * (reg >> 2) + 4 * hi;
        float bias = biasLds[128 + grow];
        float v0 = acc0[reg] + bias;
        float v1 = acc1[reg] + bias;
        float s = (v0 > 0.0f ? v0 : 0.0f) + (v1 > 0.0f ? v1 : 0.0f);
        s += __shfl_xor(s, 1);
        s += __shfl_xor(s, 2);
        s += __shfl_xor(s, 4);
        s += __shfl_xor(s, 8);
        s += __shfl_xor(s, 16);
        if (l31 == 0) out[b * OUTC + 64 + grow] = s;
    }
}

extern "C" void kernel_launch(void* const* d_in, const int* in_sizes, int n_in,
                              void* d_out, int out_size, void* d_ws, size_t ws_size,
                              hipStream_t stream) {
    const float* X  = (const float*)d_in[0];
    const float* W0 = (const float*)d_in[1];
    const float* b0 = (const float*)d_in[2];
    const float* W1 = (const float*)d_in[3];
    const float* b1 = (const float*)d_in[4];
    float* out = (float*)d_out;
    _Float16* wsw = (_Float16*)d_ws;  // 768 KB

    convert_w_kernel<<<(L0_FRAGS + L1_FRAGS + 255) / 256, 256, 0, stream>>>(W0, W1, wsw);
    cin_kernel<<<2048, 256, 0, stream>>>(X, b0, b1, wsw, out);
}

// Round 6
// 170.748 us; speedup vs baseline: 1.0400x; 1.0400x over previous
//
#include <hip/hip_runtime.h>

// CIN forward: B=2048, F=32, DIM=64, layers (128,128)
// out[b, 0:64]   = sum_d relu(W0 @ z0 + b0)[64:128, d]
// out[b, 64:192] = sum_d relu(W1 @ z1 + b1)[0:128, d]
// z0[h*32+m, d] = x[h,d]*x[m,d];  z1[h*32+m, d] = h1[h,d]*x[m,d]
//
// R6: R4 shape (32x32x16_f16, 64x64 per wave, 2 batches/block, grid 1024 =
// 4 blocks/CU) + distance-1 two-stage register prefetch (mov-free via
// unroll-2 renaming, pointer-increment addressing, peeled last iteration).

#define K0 1024
#define K1 2048
#define OUTC 192
#define L0_ELEMS (128 * K0)      // 131072
#define L1_ELEMS (128 * K1)      // 262144
#define L0_FRAGS (L0_ELEMS / 8)  // 16384
#define L1_FRAGS (L1_ELEMS / 8)  // 32768

typedef _Float16 v8h  __attribute__((ext_vector_type(8)));
typedef _Float16 v2h  __attribute__((ext_vector_type(2)));
typedef float    v16f __attribute__((ext_vector_type(16)));

// Swizzled W (f16): frag t = ks*256 + rt*64 + lane holds
//   W[row = rt*32 + (lane&31)][k = ks*16 + (lane>>5)*8 + j],  j=0..7
__global__ void convert_w_kernel(const float* __restrict__ W0,
                                 const float* __restrict__ W1,
                                 _Float16* __restrict__ wsw) {
    int t = blockIdx.x * blockDim.x + threadIdx.x;
    if (t >= L0_FRAGS + L1_FRAGS) return;
    const float* src;
    _Float16* dst;
    if (t < L0_FRAGS) {
        int lane = t & 63, rt = (t >> 6) & 3, ks = t >> 8;
        int row = rt * 32 + (lane & 31);
        int k   = ks * 16 + (lane >> 5) * 8;
        src = W0 + (size_t)row * K0 + k;
        dst = wsw + (size_t)t * 8;
    } else {
        int u = t - L0_FRAGS;
        int lane = u & 63, rt = (u >> 6) & 3, ks = u >> 8;
        int row = rt * 32 + (lane & 31);
        int k   = ks * 16 + (lane >> 5) * 8;
        src = W1 + (size_t)row * K1 + k;
        dst = wsw + L0_ELEMS + (size_t)u * 8;
    }
    #pragma unroll
    for (int j = 0; j < 8; ++j) dst[j] = (_Float16)src[j];
}

// duplicate a u16 f16 scalar into all 8 elems of a v8h (1 VALU: lshl_or)
__device__ __forceinline__ v8h dupscalar(uint32_t u) {
    uint32_t pair = (u << 16) | u;
    v2h p = __builtin_bit_cast(v2h, pair);
    return __builtin_shufflevector(p, p, 0, 1, 0, 1, 0, 1, 0, 1);
}

#define MFMA32(A, B, C) __builtin_amdgcn_mfma_f32_32x32x16_f16((A), (B), (C), 0, 0, 0)

__global__ __launch_bounds__(256, 4) void cin_kernel(
    const float* __restrict__ X,      // (B, 32, 64) fp32
    const float* __restrict__ b0,     // (128,)
    const float* __restrict__ b1,     // (128,)
    const _Float16* __restrict__ Wsw, // swizzled W0 | W1 (f16)
    float* __restrict__ out)          // (B, 192) fp32
{
    __shared__ uint16_t xS[2][32 * 64];   // x[m][d] f16 bits, 8 KB
    __shared__ uint16_t h1S[2][64 * 64];  // h1[h][d] f16 bits, 16 KB; xT overlay at init
    __shared__ float biasLds[256];        // b0 | b1

    const int tid  = threadIdx.x;
    const int wave = tid >> 6;
    const int lane = tid & 63;
    const int bi   = wave >> 1;   // batch within block
    const int rw   = wave & 1;    // row-half (0: rows 0-63, 1: rows 64-127)
    const int l31  = lane & 31;
    const int hi   = lane >> 5;   // k-octet selector
    const size_t bb = (size_t)blockIdx.x * 2;

    if (tid < 128) biasLds[tid] = b0[tid];
    else           biasLds[tid] = b1[tid - 128];

    // ---- stage x: xT (f16 pitch-40, overlaid in h1S) + xS (u16) ----
    const float* xsrc = X + bb * 2048;
    for (int i = tid; i < 4096; i += 256) {
        int bby = i >> 11, loc = i & 2047;
        int m = loc >> 6, d = loc & 63;
        _Float16 h = (_Float16)xsrc[i];
        ((_Float16*)&h1S[bby][0])[d * 40 + m] = h;
        xS[bby][m * 64 + d] = __builtin_bit_cast(uint16_t, h);
    }
    __syncthreads();

    // K-invariant B vector parts: xv[c][p] = x[m = p*16 + hi*8 .. +7][d = c*32 + l31]
    v8h xv[2][2];
    {
        const _Float16* xT = (const _Float16*)&h1S[bi][0];
        #pragma unroll
        for (int c = 0; c < 2; ++c)
            #pragma unroll
            for (int p = 0; p < 2; ++p)
                xv[c][p] = *(const v8h*)&xT[(c * 32 + l31) * 40 + p * 16 + hi * 8];
    }
    __syncthreads();  // xv reads complete before h1S overlay is rewritten

    v16f acc00, acc10, acc01, acc11;   // acc[rt][c]
    acc00 = acc10 = acc01 = acc11 = (v16f)0.0f;

    // ================= layer 0 (H=32) =================
    {
        const _Float16* Wp = Wsw + (size_t)rw * 1024 + (size_t)lane * 8;
        const uint16_t* xp = &xS[bi][0];
        // stage-in h=0
        v8h na00 = *(const v8h*)(Wp);
        v8h na10 = *(const v8h*)(Wp + 512);
        v8h na01 = *(const v8h*)(Wp + 2048);
        v8h na11 = *(const v8h*)(Wp + 2560);
        uint32_t nu0 = xp[l31], nu1 = xp[32 + l31];
        #pragma unroll 2
        for (int h = 0; h < 31; ++h) {
            v8h a00 = na00, a10 = na10, a01 = na01, a11 = na11;
            uint32_t u0 = nu0, u1 = nu1;
            Wp += 4096;
            na00 = *(const v8h*)(Wp);
            na10 = *(const v8h*)(Wp + 512);
            na01 = *(const v8h*)(Wp + 2048);
            na11 = *(const v8h*)(Wp + 2560);
            nu0 = xp[(h + 1) * 64 + l31];
            nu1 = xp[(h + 1) * 64 + 32 + l31];
            v8h s80 = dupscalar(u0), s81 = dupscalar(u1);
            v8h b00 = s80 * xv[0][0];
            acc00 = MFMA32(a00, b00, acc00);
            acc10 = MFMA32(a10, b00, acc10);
            v8h b10 = s81 * xv[1][0];
            acc01 = MFMA32(a00, b10, acc01);
            acc11 = MFMA32(a10, b10, acc11);
            v8h b01 = s80 * xv[0][1];
            acc00 = MFMA32(a01, b01, acc00);
            acc10 = MFMA32(a11, b01, acc10);
            v8h b11 = s81 * xv[1][1];
            acc01 = MFMA32(a01, b11, acc01);
            acc11 = MFMA32(a11, b11, acc11);
        }
        // peeled last h = 31
        v8h s80 = dupscalar(nu0), s81 = dupscalar(nu1);
        v8h b00 = s80 * xv[0][0];
        acc00 = MFMA32(na00, b00, acc00);
        acc10 = MFMA32(na10, b00, acc10);
        v8h b10 = s81 * xv[1][0];
        acc01 = MFMA32(na00, b10, acc01);
        acc11 = MFMA32(na10, b10, acc11);
        v8h b01 = s80 * xv[0][1];
        acc00 = MFMA32(na01, b01, acc00);
        acc10 = MFMA32(na11, b01, acc10);
        v8h b11 = s81 * xv[1][1];
        acc01 = MFMA32(na01, b11, acc01);
        acc11 = MFMA32(na11, b11, acc11);
    }

    // ---- epilogue 0 ----
    if (rw == 0) {
        // rows 0..63 -> h1S[bi] (u16)
        #pragma unroll
        for (int rt = 0; rt < 2; ++rt)
            #pragma unroll
            for (int reg = 0; reg < 16; ++reg) {
                int row = rt * 32 + (reg & 3) + 8 * (reg >> 2) + 4 * hi;
                float bias = biasLds[row];
                float v0 = (rt ? acc10[reg] : acc00[reg]) + bias;
                float v1 = (rt ? acc11[reg] : acc01[reg]) + bias;
                v0 = v0 > 0.0f ? v0 : 0.0f;
                v1 = v1 > 0.0f ? v1 : 0.0f;
                h1S[bi][row * 64 + l31]      = __builtin_bit_cast(uint16_t, (_Float16)v0);
                h1S[bi][row * 64 + 32 + l31] = __builtin_bit_cast(uint16_t, (_Float16)v1);
            }
    } else {
        // rows 64..127 -> out[b][row-64]
        #pragma unroll
        for (int rt = 0; rt < 2; ++rt)
            #pragma unroll
            for (int reg = 0; reg < 16; ++reg) {
                int grow = 64 + rt * 32 + (reg & 3) + 8 * (reg >> 2) + 4 * hi;
                float bias = biasLds[grow];
                float v0 = (rt ? acc10[reg] : acc00[reg]) + bias;
                float v1 = (rt ? acc11[reg] : acc01[reg]) + bias;
                float s = (v0 > 0.0f ? v0 : 0.0f) + (v1 > 0.0f ? v1 : 0.0f);
                s += __shfl_xor(s, 1);
                s += __shfl_xor(s, 2);
                s += __shfl_xor(s, 4);
                s += __shfl_xor(s, 8);
                s += __shfl_xor(s, 16);
                if (l31 == 0) out[(bb + bi) * OUTC + (grow - 64)] = s;
            }
    }
    __syncthreads();

    // ================= layer 1 (H=64) =================
    acc00 = acc10 = acc01 = acc11 = (v16f)0.0f;
    {
        const _Float16* Wp = Wsw + L0_ELEMS + (size_t)rw * 1024 + (size_t)lane * 8;
        const uint16_t* hp = &h1S[bi][0];
        v8h na00 = *(const v8h*)(Wp);
        v8h na10 = *(const v8h*)(Wp + 512);
        v8h na01 = *(const v8h*)(Wp + 2048);
        v8h na11 = *(const v8h*)(Wp + 2560);
        uint32_t nu0 = hp[l31], nu1 = hp[32 + l31];
        #pragma unroll 2
        for (int h = 0; h < 63; ++h) {
            v8h a00 = na00, a10 = na10, a01 = na01, a11 = na11;
            uint32_t u0 = nu0, u1 = nu1;
            Wp += 4096;
            na00 = *(const v8h*)(Wp);
            na10 = *(const v8h*)(Wp + 512);
            na01 = *(const v8h*)(Wp + 2048);
            na11 = *(const v8h*)(Wp + 2560);
            nu0 = hp[(h + 1) * 64 + l31];
            nu1 = hp[(h + 1) * 64 + 32 + l31];
            v8h s80 = dupscalar(u0), s81 = dupscalar(u1);
            v8h b00 = s80 * xv[0][0];
            acc00 = MFMA32(a00, b00, acc00);
            acc10 = MFMA32(a10, b00, acc10);
            v8h b10 = s81 * xv[1][0];
            acc01 = MFMA32(a00, b10, acc01);
            acc11 = MFMA32(a10, b10, acc11);
            v8h b01 = s80 * xv[0][1];
            acc00 = MFMA32(a01, b01, acc00);
            acc10 = MFMA32(a11, b01, acc10);
            v8h b11 = s81 * xv[1][1];
            acc01 = MFMA32(a01, b11, acc01);
            acc11 = MFMA32(a11, b11, acc11);
        }
        // peeled last h = 63
        v8h s80 = dupscalar(nu0), s81 = dupscalar(nu1);
        v8h b00 = s80 * xv[0][0];
        acc00 = MFMA32(na00, b00, acc00);
        acc10 = MFMA32(na10, b00, acc10);
        v8h b10 = s81 * xv[1][0];
        acc01 = MFMA32(na00, b10, acc01);
        acc11 = MFMA32(na10, b10, acc11);
        v8h b01 = s80 * xv[0][1];
        acc00 = MFMA32(na01, b01, acc00);
        acc10 = MFMA32(na11, b01, acc10);
        v8h b11 = s81 * xv[1][1];
        acc01 = MFMA32(na01, b11, acc01);
        acc11 = MFMA32(na11, b11, acc11);
    }

    // ---- epilogue 1: all 128 rows -> out[b][64 + row] ----
    #pragma unroll
    for (int rt = 0; rt < 2; ++rt)
        #pragma unroll
        for (int reg = 0; reg < 16; ++reg) {
            int grow = rw * 64 + rt * 32 + (reg & 3) + 8 * (reg >> 2) + 4 * hi;
            float bias = biasLds[128 + grow];
            float v0 = (rt ? acc10[reg] : acc00[reg]) + bias;
            float v1 = (rt ? acc11[reg] : acc01[reg]) + bias;
            float s = (v0 > 0.0f ? v0 : 0.0f) + (v1 > 0.0f ? v1 : 0.0f);
            s += __shfl_xor(s, 1);
            s += __shfl_xor(s, 2);
            s += __shfl_xor(s, 4);
            s += __shfl_xor(s, 8);
            s += __shfl_xor(s, 16);
            if (l31 == 0) out[(bb + bi) * OUTC + 64 + grow] = s;
        }
}

extern "C" void kernel_launch(void* const* d_in, const int* in_sizes, int n_in,
                              void* d_out, int out_size, void* d_ws, size_t ws_size,
                              hipStream_t stream) {
    const float* X  = (const float*)d_in[0];
    const float* W0 = (const float*)d_in[1];
    const float* b0 = (const float*)d_in[2];
    const float* W1 = (const float*)d_in[3];
    const float* b1 = (const float*)d_in[4];
    float* out = (float*)d_out;
    _Float16* wsw = (_Float16*)d_ws;  // 768 KB

    convert_w_kernel<<<(L0_FRAGS + L1_FRAGS + 255) / 256, 256, 0, stream>>>(W0, W1, wsw);
    cin_kernel<<<1024, 256, 0, stream>>>(X, b0, b1, wsw, out);
}